// Round 2
// baseline (499.269 us; speedup 1.0000x reference)
//
#include <hip/hip_runtime.h>
#include <cmath>

#define NLEVELS 16
#define TBL     (1u << 19)
#define HMASK   0x7FFFFu
#define NPTS    524288

typedef float v4f __attribute__((ext_vector_type(4)));

struct LevelParams {
    float cell[NLEVELS];   // fp32 value of 1.0f / (float)RES[l], matching numpy
};

__global__ __launch_bounds__(256) void ngp_encode(
    const float* __restrict__ xyz,
    const float* __restrict__ tables,
    float* __restrict__ out,
    LevelParams lp)
{
    const int n = blockIdx.x * 256 + threadIdx.x;

    // xyz is [N,3] row-major; 3 consecutive fp32 per point
    const float x = xyz[3 * n + 0];
    const float y = xyz[3 * n + 1];
    const float z = xyz[3 * n + 2];

    float acc[2 * NLEVELS];

    const float2* __restrict__ tab_base = (const float2*)tables;

    #pragma unroll
    for (int l = 0; l < NLEVELS; ++l) {
        const float cell = lp.cell[l];
        // EXACT replication of reference: u = (x - 0) / cell, IEEE fp32 divide
        const float ux = x / cell;
        const float uy = y / cell;
        const float uz = z / cell;
        const float fx = floorf(ux);
        const float fy = floorf(uy);
        const float fz = floorf(uz);
        const float dx = ux - fx;
        const float dy = uy - fy;
        const float dz = uz - fz;

        const unsigned ix = (unsigned)(int)fx;
        const unsigned iy = (unsigned)(int)fy;
        const unsigned iz = (unsigned)(int)fz;

        // hash components: PI = {1, 2654435761, 805459861}, uint32 wrap
        const unsigned hx0 = ix;
        const unsigned hx1 = ix + 1u;
        const unsigned hy0 = iy * 2654435761u;
        const unsigned hy1 = (iy + 1u) * 2654435761u;
        const unsigned hz0 = iz * 805459861u;
        const unsigned hz1 = (iz + 1u) * 805459861u;

        // corner order (VERTS): v = (bx,by,bz) listed z-fastest
        const unsigned h0 = (hx0 ^ hy0 ^ hz0) & HMASK; // 0,0,0
        const unsigned h1 = (hx0 ^ hy0 ^ hz1) & HMASK; // 0,0,1
        const unsigned h2 = (hx0 ^ hy1 ^ hz0) & HMASK; // 0,1,0
        const unsigned h3 = (hx0 ^ hy1 ^ hz1) & HMASK; // 0,1,1
        const unsigned h4 = (hx1 ^ hy0 ^ hz0) & HMASK; // 1,0,0
        const unsigned h5 = (hx1 ^ hy0 ^ hz1) & HMASK; // 1,0,1
        const unsigned h6 = (hx1 ^ hy1 ^ hz0) & HMASK; // 1,1,0
        const unsigned h7 = (hx1 ^ hy1 ^ hz1) & HMASK; // 1,1,1

        const float2* __restrict__ tab = tab_base + ((size_t)l << 19);

        // issue all 8 gathers back-to-back (independent, latency overlap)
        const float2 e0 = tab[h0];
        const float2 e1 = tab[h1];
        const float2 e2 = tab[h2];
        const float2 e3 = tab[h3];
        const float2 e4 = tab[h4];
        const float2 e5 = tab[h5];
        const float2 e6 = tab[h6];
        const float2 e7 = tab[h7];

        // trilinear weights, multiply order matches numpy prod over last axis:
        // ((wx * wy) * wz)
        const float wx0 = 1.0f - dx;
        const float wy0 = 1.0f - dy;
        const float wz0 = 1.0f - dz;

        const float p00 = wx0 * wy0;
        const float p01 = wx0 * dy;
        const float p10 = dx * wy0;
        const float p11 = dx * dy;

        const float w0 = p00 * wz0;
        const float w1 = p00 * dz;
        const float w2 = p01 * wz0;
        const float w3 = p01 * dz;
        const float w4 = p10 * wz0;
        const float w5 = p10 * dz;
        const float w6 = p11 * wz0;
        const float w7 = p11 * dz;

        float c0 = w0 * e0.x;
        float c1 = w0 * e0.y;
        c0 += w1 * e1.x;  c1 += w1 * e1.y;
        c0 += w2 * e2.x;  c1 += w2 * e2.y;
        c0 += w3 * e3.x;  c1 += w3 * e3.y;
        c0 += w4 * e4.x;  c1 += w4 * e4.y;
        c0 += w5 * e5.x;  c1 += w5 * e5.y;
        c0 += w6 * e6.x;  c1 += w6 * e6.y;
        c0 += w7 * e7.x;  c1 += w7 * e7.y;

        acc[2 * l + 0] = c0;
        acc[2 * l + 1] = c1;
    }

    // each point's output is exactly one 128-B line: 8 x float4, nontemporal
    // (keeps L2 clean for the hash tables)
    v4f* o4 = (v4f*)(out + (size_t)n * 32);
    #pragma unroll
    for (int j = 0; j < 8; ++j) {
        v4f v = { acc[4 * j + 0], acc[4 * j + 1],
                  acc[4 * j + 2], acc[4 * j + 3] };
        __builtin_nontemporal_store(v, o4 + j);
    }
}

extern "C" void kernel_launch(void* const* d_in, const int* in_sizes, int n_in,
                              void* d_out, int out_size, void* d_ws, size_t ws_size,
                              hipStream_t stream) {
    const float* xyz    = (const float*)d_in[0];
    const float* tables = (const float*)d_in[1];
    float* out          = (float*)d_out;

    // Compute RES exactly as CPython does (glibc double exp/log/pow), then
    // cell = 1/RES in fp32 exactly as numpy float32 division.
    LevelParams lp;
    const double B = std::exp((std::log(2048.0) - std::log(16.0)) / 15.0);
    for (int i = 0; i < NLEVELS; ++i) {
        const double r = std::floor(16.0 * std::pow(B, (double)i));
        const float rf = (float)r;
        lp.cell[i] = 1.0f / rf;
    }

    dim3 grid(NPTS / 256);
    dim3 block(256);
    hipLaunchKernelGGL(ngp_encode, grid, block, 0, stream,
                       xyz, tables, out, lp);
}

// Round 4
// 381.059 us; speedup vs baseline: 1.3102x; 1.3102x over previous
//
#include <hip/hip_runtime.h>
#include <cmath>

#define NLEVELS 16
#define TBL     (1u << 19)
#define HMASK   0x7FFFFu
#define NPTS    524288
#define NCHUNK  (NPTS / 256)          // 2048 point-chunks of 256

typedef float v4f __attribute__((ext_vector_type(4)));

struct LevelParams {
    float cell[NLEVELS];   // fp32 value of 1.0f / (float)RES[l], matching numpy
};

// ---------------------------------------------------------------------------
// Shared per-level compute: EXACT replication of the numpy fp32 chain.
// ---------------------------------------------------------------------------
__device__ __forceinline__ float2 level_interp(
    float x, float y, float z, float cell,
    const float2* __restrict__ tab)
{
    const float ux = x / cell;
    const float uy = y / cell;
    const float uz = z / cell;
    const float fx = floorf(ux);
    const float fy = floorf(uy);
    const float fz = floorf(uz);
    const float dx = ux - fx;
    const float dy = uy - fy;
    const float dz = uz - fz;

    const unsigned ix = (unsigned)(int)fx;
    const unsigned iy = (unsigned)(int)fy;
    const unsigned iz = (unsigned)(int)fz;

    const unsigned hx0 = ix;
    const unsigned hx1 = ix + 1u;
    const unsigned hy0 = iy * 2654435761u;
    const unsigned hy1 = (iy + 1u) * 2654435761u;
    const unsigned hz0 = iz * 805459861u;
    const unsigned hz1 = (iz + 1u) * 805459861u;

    const unsigned h0 = (hx0 ^ hy0 ^ hz0) & HMASK;
    const unsigned h1 = (hx0 ^ hy0 ^ hz1) & HMASK;
    const unsigned h2 = (hx0 ^ hy1 ^ hz0) & HMASK;
    const unsigned h3 = (hx0 ^ hy1 ^ hz1) & HMASK;
    const unsigned h4 = (hx1 ^ hy0 ^ hz0) & HMASK;
    const unsigned h5 = (hx1 ^ hy0 ^ hz1) & HMASK;
    const unsigned h6 = (hx1 ^ hy1 ^ hz0) & HMASK;
    const unsigned h7 = (hx1 ^ hy1 ^ hz1) & HMASK;

    const float2 e0 = tab[h0];
    const float2 e1 = tab[h1];
    const float2 e2 = tab[h2];
    const float2 e3 = tab[h3];
    const float2 e4 = tab[h4];
    const float2 e5 = tab[h5];
    const float2 e6 = tab[h6];
    const float2 e7 = tab[h7];

    const float wx0 = 1.0f - dx;
    const float wy0 = 1.0f - dy;
    const float wz0 = 1.0f - dz;

    const float p00 = wx0 * wy0;
    const float p01 = wx0 * dy;
    const float p10 = dx * wy0;
    const float p11 = dx * dy;

    const float w0 = p00 * wz0;
    const float w1 = p00 * dz;
    const float w2 = p01 * wz0;
    const float w3 = p01 * dz;
    const float w4 = p10 * wz0;
    const float w5 = p10 * dz;
    const float w6 = p11 * wz0;
    const float w7 = p11 * dz;

    float c0 = w0 * e0.x;
    float c1 = w0 * e0.y;
    c0 += w1 * e1.x;  c1 += w1 * e1.y;
    c0 += w2 * e2.x;  c1 += w2 * e2.y;
    c0 += w3 * e3.x;  c1 += w3 * e3.y;
    c0 += w4 * e4.x;  c1 += w4 * e4.y;
    c0 += w5 * e5.x;  c1 += w5 * e5.y;
    c0 += w6 * e6.x;  c1 += w6 * e6.y;
    c0 += w7 * e7.x;  c1 += w7 * e7.y;

    return make_float2(c0, c1);
}

// ---------------------------------------------------------------------------
// Phase 1: one block = 256 points x ONE level.
// blockIdx encoding pins level%8 to XCD (round-robin dispatch: XCD = b % 8)
// and splits levels {0-7} / {8-15} into two temporal phases so each XCD's
// 4 MB L2 holds exactly one 4 MB table at a time.
//   b = phase*16384 + chunk*8 + (level%8)
// ---------------------------------------------------------------------------
__global__ __launch_bounds__(256) void ngp_phase1(
    const float* __restrict__ xyz,
    const float* __restrict__ tables,
    float2* __restrict__ ws,          // [L][N] float2
    LevelParams lp)
{
    const unsigned b = blockIdx.x;
    const int level = (int)(((b >> 14) << 3) | (b & 7u));
    const int chunk = (int)((b >> 3) & (NCHUNK - 1u));
    const int n = chunk * 256 + threadIdx.x;

    const float x = xyz[3 * n + 0];
    const float y = xyz[3 * n + 1];
    const float z = xyz[3 * n + 2];

    const float cell = lp.cell[level];
    const float2* __restrict__ tab = (const float2*)tables + ((size_t)level << 19);

    const float2 c = level_interp(x, y, z, cell, tab);

    // [l][n] layout: lanes write 8B each, 512B contiguous per wave
    ws[(size_t)level * NPTS + n] = c;
}

// ---------------------------------------------------------------------------
// Phase 2: transpose ws[l][n][2] -> out[n][32].
// One thread per output float4 (levels 2k,2k+1 of point n).
// Stores: fully coalesced (1 KB/wave). Loads: 8 x 64B segments per instr.
// ---------------------------------------------------------------------------
__global__ __launch_bounds__(256) void ngp_phase2(
    const float2* __restrict__ ws,
    float* __restrict__ out)
{
    const unsigned j = blockIdx.x * 256 + threadIdx.x;   // out float4 index
    const unsigned n = j >> 3;
    const unsigned k = j & 7u;                           // levels 2k, 2k+1

    const float2 a = ws[(size_t)(2u * k)      * NPTS + n];
    const float2 b = ws[(size_t)(2u * k + 1u) * NPTS + n];

    v4f v = { a.x, a.y, b.x, b.y };
    *(v4f*)(out + (size_t)j * 4) = v;
}

// ---------------------------------------------------------------------------
// Fallback single-kernel (used only if ws_size is too small): round-0 kernel
// with plain (not nontemporal) stores.
// ---------------------------------------------------------------------------
__global__ __launch_bounds__(256) void ngp_encode(
    const float* __restrict__ xyz,
    const float* __restrict__ tables,
    float* __restrict__ out,
    LevelParams lp)
{
    const int n = blockIdx.x * 256 + threadIdx.x;
    const float x = xyz[3 * n + 0];
    const float y = xyz[3 * n + 1];
    const float z = xyz[3 * n + 2];

    float acc[2 * NLEVELS];
    const float2* __restrict__ tab_base = (const float2*)tables;

    #pragma unroll
    for (int l = 0; l < NLEVELS; ++l) {
        const float2 c = level_interp(x, y, z, lp.cell[l],
                                      tab_base + ((size_t)l << 19));
        acc[2 * l + 0] = c.x;
        acc[2 * l + 1] = c.y;
    }

    v4f* o4 = (v4f*)(out + (size_t)n * 32);
    #pragma unroll
    for (int j = 0; j < 8; ++j) {
        v4f v = { acc[4 * j + 0], acc[4 * j + 1],
                  acc[4 * j + 2], acc[4 * j + 3] };
        o4[j] = v;
    }
}

extern "C" void kernel_launch(void* const* d_in, const int* in_sizes, int n_in,
                              void* d_out, int out_size, void* d_ws, size_t ws_size,
                              hipStream_t stream) {
    const float* xyz    = (const float*)d_in[0];
    const float* tables = (const float*)d_in[1];
    float* out          = (float*)d_out;

    // Compute RES exactly as CPython does (glibc double exp/log/pow), then
    // cell = 1/RES in fp32 exactly as numpy float32 division.
    LevelParams lp;
    const double B = std::exp((std::log(2048.0) - std::log(16.0)) / 15.0);
    for (int i = 0; i < NLEVELS; ++i) {
        const double r = std::floor(16.0 * std::pow(B, (double)i));
        lp.cell[i] = 1.0f / (float)r;
    }

    const size_t ws_needed = (size_t)NLEVELS * NPTS * sizeof(float2); // 64 MB

    if (ws_size >= ws_needed) {
        float2* ws = (float2*)d_ws;
        hipLaunchKernelGGL(ngp_phase1, dim3(NLEVELS * NCHUNK), dim3(256), 0, stream,
                           xyz, tables, ws, lp);
        // one thread per output float4: NPTS*8 threads total
        hipLaunchKernelGGL(ngp_phase2, dim3(NPTS * 8 / 256), dim3(256), 0, stream,
                           ws, out);
    } else {
        hipLaunchKernelGGL(ngp_encode, dim3(NPTS / 256), dim3(256), 0, stream,
                           xyz, tables, out, lp);
    }
}